// Round 23
// baseline (53.073 us; speedup 1.0000x reference)
//
#include <hip/hip_runtime.h>
#include <hip/hip_bf16.h>

#define SEQ 4096
#define MTOT 16384

typedef float f32x4  __attribute__((ext_vector_type(4)));
typedef float f32x16 __attribute__((ext_vector_type(16)));
typedef _Float16 f16;
typedef _Float16 f16x4 __attribute__((ext_vector_type(4)));
typedef _Float16 f16x8 __attribute__((ext_vector_type(8)));
typedef unsigned int   u32;
typedef unsigned int   u32x2 __attribute__((ext_vector_type(2)));
typedef unsigned short u16;

// ws byte offsets — Q/K/V/W in MFMA fragment-linear layout.
// Q_lin [qhalf(512)][ch(4)][lane(64)][8] : lane(l31,h) = Q[qhalf*32+l31][ch*16+h*8+j]
// K_lin [tile(512)][ch(4)][lane(64)][8]  : lane(l31,h) = K[tile*32+l31][ch*16+h*8+j]
// V_lin [tile(512)][db2][p2][lane(64)][8]
// W_lin [s(12)][step(16)][lane(64)][8]   (Wq pre-scaled by 0.125*log2e)
static constexpr size_t QL_B   = 0;           // 2MB
static constexpr size_t KL_B   = 2u << 20;    // 2MB
static constexpr size_t VL_B   = 4u << 20;    // 2MB
static constexpr size_t WL_B   = 6u << 20;    // 192KB

__device__ __forceinline__ u16 h16(float v) { return __builtin_bit_cast(u16, (f16)v); }
__device__ __forceinline__ u32 pkrtz(float a, float b) {
  return __builtin_bit_cast(u32, __builtin_amdgcn_cvt_pkrtz(a, b));
}
__device__ __forceinline__ float ex2(float x) { return __builtin_amdgcn_exp2f(x); }

// ---------------- W fp32 -> fragment-linear fp16 ----------------
__global__ __launch_bounds__(256) void wconv_kernel(const float* __restrict__ Wq,
                                                    const float* __restrict__ Wk,
                                                    const float* __restrict__ Wv,
                                                    u16* __restrict__ wlin) {
  const float QSC = 0.18033688011112042f;  // 0.125 * log2(e)
  int e = blockIdx.x * 256 + threadIdx.x;
  int flat = e * 4;
  int colg = flat >> 9;
  int k0   = flat & 511;
  int mat  = colg >> 6;
  const float* W = (mat == 0) ? Wq : (mat == 1 ? Wk : Wv);
  f32x4 v = *(const f32x4*)(W + (size_t)(colg & 63) * 512 + k0);
  if (mat == 0) v *= QSC;
  int s = colg >> 4, r16 = colg & 15;
  int step = k0 >> 5, g = (k0 & 31) >> 3, jb = k0 & 7;
  __attribute__((aligned(8))) u16 b[4];
#pragma unroll
  for (int j = 0; j < 4; ++j) b[j] = h16(v[j]);
  *(uint2*)(wlin + ((size_t)(s * 16 + step) * 64 + g * 16 + r16) * 8 + jb) = *(uint2*)b;
}

// ---------------- QKV projection (r14/r19 proven) ----------------
__global__ __launch_bounds__(256, 4) void proj_kernel(const float* __restrict__ x,
                                                      const u16* __restrict__ wlin,
                                                      u16* __restrict__ ws) {
  __shared__ __attribute__((aligned(16))) u16 xl[8192];
  float* scr = (float*)xl;

  const int tid  = threadIdx.x;
  const int blk  = blockIdx.x;
  const int lane = tid & 63;
  const int ng   = tid >> 6;
  const int r16  = lane & 15;
  const int g    = lane >> 4;
  const int m0   = blk * 16;

#pragma unroll
  for (int i = 0; i < 8; ++i) {
    int f = tid * 4 + i * 1024;
    int row = f >> 9, k0 = f & 511;
    f32x4 v = *(const f32x4*)(x + (size_t)m0 * 512 + f);
    __attribute__((aligned(8))) u16 b[4];
#pragma unroll
    for (int j = 0; j < 4; ++j) b[j] = h16(v[j]);
    int ln = ((k0 & 31) >> 3) * 16 + row;
    *(uint2*)(xl + ((size_t)(k0 >> 5) * 64 + ln) * 8 + (k0 & 7)) = *(uint2*)b;
  }
  __syncthreads();

  f32x4 acc[3];
#pragma unroll
  for (int s = 0; s < 3; ++s) acc[s] = (f32x4){0.f, 0.f, 0.f, 0.f};

#pragma unroll 2
  for (int step = 0; step < 16; ++step) {
    f16x8 a = *(const f16x8*)(xl + ((size_t)step * 64 + lane) * 8);
#pragma unroll
    for (int s = 0; s < 3; ++s) {
      int sg = ng * 3 + s;
      f16x8 b = *(const f16x8*)(wlin + ((size_t)(sg * 16 + step) * 64 + lane) * 8);
      acc[s] = __builtin_amdgcn_mfma_f32_16x16x32_f16(a, b, acc[s], 0, 0, 0);
    }
  }
  __syncthreads();

#pragma unroll
  for (int s = 0; s < 3; ++s)
#pragma unroll
    for (int rr = 0; rr < 4; ++rr)
      scr[(g * 4 + rr) * 193 + ng * 48 + s * 16 + r16] = acc[s][rr];
  __syncthreads();

  u16* Ql = ws + (QL_B >> 1);
  u16* Kl = ws + (KL_B >> 1);
  u16* Vl = ws + (VL_B >> 1);
  const int batch = m0 >> 12;
  const int tile  = (m0 >> 5) & 127;
  const int half  = (m0 >> 4) & 1;

  {
    int t2 = tid & 127;
    int r  = t2 & 15, hh = (t2 >> 4) & 1, ch = t2 >> 5;
    int l31 = half * 16 + r;
    __attribute__((aligned(16))) u16 b[8];
    if (tid < 128) {
#pragma unroll
      for (int j = 0; j < 8; ++j) b[j] = h16(scr[r * 193 + 64 + ch * 16 + hh * 8 + j]);
      *(uint4*)(Kl + ((size_t)((batch * 128 + tile) * 4 + ch) * 64 + hh * 32 + l31) * 8) =
          *(uint4*)b;
    } else {
#pragma unroll
      for (int j = 0; j < 8; ++j) b[j] = h16(scr[r * 193 + ch * 16 + hh * 8 + j]);
      int qhalf = (m0 >> 5);
      *(uint4*)(Ql + ((size_t)(qhalf * 4 + ch) * 64 + hh * 32 + l31) * 8) = *(uint4*)b;
    }
  }
  {
    int z = tid & 1, l31 = (tid >> 1) & 31, hh = (tid >> 6) & 1, db = tid >> 7;
    int d = db * 32 + l31;
    __attribute__((aligned(8))) u16 b[4];
#pragma unroll
    for (int j = 0; j < 4; ++j) b[j] = h16(scr[(8 * z + 4 * hh + j) * 193 + 128 + d]);
    *(uint2*)(Vl + ((size_t)(((batch * 128 + tile) * 2 + db) * 2 + half) * 64 + hh * 32 + l31) *
                       8 + z * 4) = *(uint2*)b;
  }
}

// ---------------- flash attention: 3-deep all-register K+V prefetch ----------------
// 256 blocks (XCD-bijective) x 512 thr (8 waves = 2 qg x 4 kq). Wave (qg,kq): q rows
// qb*64+qg*32, kv quarter kq*1024 = 32 tiles. K AND V in 3-deep register rotation
// (A/B/C, static names): tile t's loads get TWO bodies of latency cover. No main-loop
// LDS/barriers; setprio around MFMA clusters (waves phase-independent = m191 regime).
__global__ __launch_bounds__(512, 2) void attn_kernel(const u16* __restrict__ ws,
                                                      float* __restrict__ out) {
  __shared__ __attribute__((aligned(16))) float po[4][32][68];   // 34.8KB
  __shared__ float mls[8][32][2];                                // 2KB

  const int tid  = threadIdx.x;
  const int w    = tid >> 6;
  const int lane = tid & 63;
  const int l31  = lane & 31;
  const int h    = lane >> 5;
  const int qg   = w >> 2;
  const int kq   = w & 3;
  const int bx   = blockIdx.x;
  const int qb   = (bx & 7) * 32 + (bx >> 3);  // bijective: XCD gets contiguous q range
  const int bb   = qb >> 6;                    // batch

  const u16* Ql = ws + (QL_B >> 1);
  const u16* Kl = ws + (KL_B >> 1);
  const u16* Vl = ws + (VL_B >> 1);

  f16x8 qf[4];
#pragma unroll
  for (int ch = 0; ch < 4; ++ch)
    qf[ch] = *(const f16x8*)(Ql + ((size_t)((qb * 2 + qg) * 4 + ch) * 64 + lane) * 8);

  f32x16 oacc[2];
#pragma unroll
  for (int db = 0; db < 2; ++db)
#pragma unroll
    for (int r = 0; r < 16; ++r) oacc[db][r] = 0.f;
  float mrun = -INFINITY, lrun = 0.f;
  const float RTHR = 11.0f;

  const int t0 = bb * 128 + kq * 32;  // wave's private 32-tile kv range

  f16x8 kA[4], kB[4], kC[4], vA[2][2], vB[2][2], vC[2][2];
  auto loadK = [&](f16x8(&kk)[4], int t) {
#pragma unroll
    for (int ch = 0; ch < 4; ++ch)
      kk[ch] = *(const f16x8*)(Kl + (size_t)t * 2048 + (ch * 64 + lane) * 8);
  };
  auto loadV = [&](f16x8(&vv)[2][2], int t) {
#pragma unroll
    for (int db = 0; db < 2; ++db)
#pragma unroll
      for (int pp = 0; pp < 2; ++pp)
        vv[db][pp] = *(const f16x8*)(Vl + (size_t)t * 2048 + ((db * 2 + pp) * 64 + lane) * 8);
  };

  auto body = [&](f16x8(&kc)[4], f16x8(&kp)[4], f16x8(&vc)[2][2], f16x8(&vp)[2][2], int t,
                  bool pf) {
    if (pf) {  // prefetch tile t+2 (two bodies of cover)
      loadK(kp, t + 2);
      loadV(vp, t + 2);
    }

    // S^T = K * Q^T (compiler inserts counted vmcnt before first use of kc)
    f32x16 sac;
#pragma unroll
    for (int r = 0; r < 16; ++r) sac[r] = 0.f;
    __builtin_amdgcn_s_setprio(1);
#pragma unroll
    for (int ch = 0; ch < 4; ++ch)
      sac = __builtin_amdgcn_mfma_f32_32x32x16_f16(kc[ch], qf[ch], sac, 0, 0, 0);
    __builtin_amdgcn_s_setprio(0);

    // lane-local defer-max softmax, tree max
    float t8[8];
#pragma unroll
    for (int r = 0; r < 8; ++r) t8[r] = fmaxf(sac[2 * r], sac[2 * r + 1]);
    float t4a = fmaxf(t8[0], t8[1]), t4b = fmaxf(t8[2], t8[3]);
    float t4c = fmaxf(t8[4], t8[5]), t4d = fmaxf(t8[6], t8[7]);
    float mt = fmaxf(fmaxf(t4a, t4b), fmaxf(t4c, t4d));
    if (__any(mt > mrun + RTHR)) {
      float mtw  = fmaxf(mt, __shfl_xor(mt, 32));
      float nm   = fmaxf(mrun, mtw);
      float corr = ex2(mrun - nm);
      lrun *= corr;
      mrun = nm;
#pragma unroll
      for (int db = 0; db < 2; ++db)
#pragma unroll
        for (int r = 0; r < 16; ++r) oacc[db][r] *= corr;
    }
#pragma unroll
    for (int r = 0; r < 16; ++r) sac[r] = ex2(sac[r] - mrun);
    float s4[4];
#pragma unroll
    for (int r = 0; r < 4; ++r)
      s4[r] = (sac[4 * r] + sac[4 * r + 1]) + (sac[4 * r + 2] + sac[4 * r + 3]);
    lrun += (s4[0] + s4[1]) + (s4[2] + s4[3]);

    // P -> B-fragments of 32x32x8 directly (no cross-lane ops)
    f16x4 pb[4];
#pragma unroll
    for (int c = 0; c < 4; ++c) {
      u32x2 pk;
      pk[0] = pkrtz(sac[4 * c + 0], sac[4 * c + 1]);
      pk[1] = pkrtz(sac[4 * c + 2], sac[4 * c + 3]);
      pb[c] = __builtin_bit_cast(f16x4, pk);
    }

    // O^T += V^T * P^T
    __builtin_amdgcn_s_setprio(1);
#pragma unroll
    for (int db = 0; db < 2; ++db)
#pragma unroll
      for (int pp = 0; pp < 2; ++pp) {
        f16x4 vlo = __builtin_shufflevector(vc[db][pp], vc[db][pp], 0, 1, 2, 3);
        f16x4 vhi = __builtin_shufflevector(vc[db][pp], vc[db][pp], 4, 5, 6, 7);
        oacc[db] = __builtin_amdgcn_mfma_f32_32x32x8f16(vlo, pb[2 * pp], oacc[db], 0, 0, 0);
        oacc[db] = __builtin_amdgcn_mfma_f32_32x32x8f16(vhi, pb[2 * pp + 1], oacc[db], 0, 0, 0);
      }
    __builtin_amdgcn_s_setprio(0);
  };

  loadK(kA, t0);
  loadV(vA, t0);
  loadK(kB, t0 + 1);
  loadV(vB, t0 + 1);
#pragma unroll 1
  for (int p = 0; p < 10; ++p) {
    body(kA, kC, vA, vC, t0 + 3 * p + 0, true);
    body(kB, kA, vB, vA, t0 + 3 * p + 1, true);
    body(kC, kB, vC, vB, t0 + 3 * p + 2, true);
  }
  body(kA, kC, vA, vC, t0 + 30, false);  // loaded at t+28's prefetch
  body(kB, kC, vB, vC, t0 + 31, false);  // loaded at t+29's prefetch

  lrun += __shfl_xor(lrun, 32);

  // ---- two-pass in-LDS merge ----
  if (h == 0) {
    mls[w][l31][0] = mrun;
    mls[w][l31][1] = lrun;
  }
  __syncthreads();

#pragma unroll 1
  for (int g = 0; g < 2; ++g) {
    if (qg == g) {
      float mg = -INFINITY;
#pragma unroll
      for (int k2 = 0; k2 < 4; ++k2) mg = fmaxf(mg, mls[g * 4 + k2][l31][0]);
      float wgt = ex2(mrun - mg);
#pragma unroll
      for (int db = 0; db < 2; ++db)
#pragma unroll
        for (int gg = 0; gg < 4; ++gg) {
          f32x4 v = {oacc[db][4 * gg + 0] * wgt, oacc[db][4 * gg + 1] * wgt,
                     oacc[db][4 * gg + 2] * wgt, oacc[db][4 * gg + 3] * wgt};
          *(f32x4*)(&po[kq][l31][db * 32 + 8 * gg + 4 * h]) = v;
        }
    }
    __syncthreads();
    {
      int q = tid >> 4, c4 = (tid & 15) * 4;  // 512 threads = 32 rows x 16 col-groups
      float m2 = -INFINITY;
#pragma unroll
      for (int k2 = 0; k2 < 4; ++k2) m2 = fmaxf(m2, mls[g * 4 + k2][q][0]);
      float l2 = 0.f;
#pragma unroll
      for (int k2 = 0; k2 < 4; ++k2)
        l2 += mls[g * 4 + k2][q][1] * ex2(mls[g * 4 + k2][q][0] - m2);
      f32x4 s = (f32x4){0.f, 0.f, 0.f, 0.f};
#pragma unroll
      for (int k2 = 0; k2 < 4; ++k2) s += *(const f32x4*)(&po[k2][q][c4]);
      s *= (1.f / l2);
      *(f32x4*)(out + (size_t)(qb * 64 + g * 32 + q) * 64 + c4) = s;
    }
    __syncthreads();
  }
}

extern "C" void kernel_launch(void* const* d_in, const int* in_sizes, int n_in,
                              void* d_out, int out_size, void* d_ws, size_t ws_size,
                              hipStream_t stream) {
  const float* x  = (const float*)d_in[0];
  const float* Wq = (const float*)d_in[1];
  const float* Wk = (const float*)d_in[2];
  const float* Wv = (const float*)d_in[3];
  u16* ws = (u16*)d_ws;
  (void)in_sizes; (void)n_in; (void)out_size; (void)ws_size;

  wconv_kernel<<<96, 256, 0, stream>>>(Wq, Wk, Wv, ws + (WL_B >> 1));
  proj_kernel<<<1024, 256, 0, stream>>>(x, ws + (WL_B >> 1), ws);
  attn_kernel<<<256, 512, 0, stream>>>(ws, (float*)d_out);
}

// Round 24
// 52.595 us; speedup vs baseline: 1.0091x; 1.0091x over previous
//
#include <hip/hip_runtime.h>
#include <hip/hip_bf16.h>

#define SEQ 4096
#define MTOT 16384

typedef float f32x4  __attribute__((ext_vector_type(4)));
typedef float f32x16 __attribute__((ext_vector_type(16)));
typedef _Float16 f16;
typedef _Float16 f16x4 __attribute__((ext_vector_type(4)));
typedef _Float16 f16x8 __attribute__((ext_vector_type(8)));
typedef unsigned int   u32;
typedef unsigned int   u32x2 __attribute__((ext_vector_type(2)));
typedef unsigned short u16;

// ws byte offsets — Q/K/V/W in MFMA fragment-linear layout.
// Q_lin [qhalf(512)][ch(4)][lane(64)][8] : lane(l31,h) = Q[qhalf*32+l31][ch*16+h*8+j]
// K_lin [tile(512)][ch(4)][lane(64)][8]  : lane(l31,h) = K[tile*32+l31][ch*16+h*8+j]
// V_lin [tile(512)][db2][p2][lane(64)][8]
// W_lin [s(12)][step(16)][lane(64)][8]   (Wq pre-scaled by 0.125*log2e)
static constexpr size_t QL_B   = 0;           // 2MB
static constexpr size_t KL_B   = 2u << 20;    // 2MB
static constexpr size_t VL_B   = 4u << 20;    // 2MB
static constexpr size_t WL_B   = 6u << 20;    // 192KB

__device__ __forceinline__ u16 h16(float v) { return __builtin_bit_cast(u16, (f16)v); }
__device__ __forceinline__ u32 pkrtz(float a, float b) {
  return __builtin_bit_cast(u32, __builtin_amdgcn_cvt_pkrtz(a, b));
}
__device__ __forceinline__ float ex2(float x) { return __builtin_amdgcn_exp2f(x); }

// ---------------- W fp32 -> fragment-linear fp16 ----------------
__global__ __launch_bounds__(256) void wconv_kernel(const float* __restrict__ Wq,
                                                    const float* __restrict__ Wk,
                                                    const float* __restrict__ Wv,
                                                    u16* __restrict__ wlin) {
  const float QSC = 0.18033688011112042f;  // 0.125 * log2(e)
  int e = blockIdx.x * 256 + threadIdx.x;
  int flat = e * 4;
  int colg = flat >> 9;
  int k0   = flat & 511;
  int mat  = colg >> 6;
  const float* W = (mat == 0) ? Wq : (mat == 1 ? Wk : Wv);
  f32x4 v = *(const f32x4*)(W + (size_t)(colg & 63) * 512 + k0);
  if (mat == 0) v *= QSC;
  int s = colg >> 4, r16 = colg & 15;
  int step = k0 >> 5, g = (k0 & 31) >> 3, jb = k0 & 7;
  __attribute__((aligned(8))) u16 b[4];
#pragma unroll
  for (int j = 0; j < 4; ++j) b[j] = h16(v[j]);
  *(uint2*)(wlin + ((size_t)(s * 16 + step) * 64 + g * 16 + r16) * 8 + jb) = *(uint2*)b;
}

// ---------------- QKV projection (r14/r19 proven) ----------------
__global__ __launch_bounds__(256, 4) void proj_kernel(const float* __restrict__ x,
                                                      const u16* __restrict__ wlin,
                                                      u16* __restrict__ ws) {
  __shared__ __attribute__((aligned(16))) u16 xl[8192];
  float* scr = (float*)xl;

  const int tid  = threadIdx.x;
  const int blk  = blockIdx.x;
  const int lane = tid & 63;
  const int ng   = tid >> 6;
  const int r16  = lane & 15;
  const int g    = lane >> 4;
  const int m0   = blk * 16;

#pragma unroll
  for (int i = 0; i < 8; ++i) {
    int f = tid * 4 + i * 1024;
    int row = f >> 9, k0 = f & 511;
    f32x4 v = *(const f32x4*)(x + (size_t)m0 * 512 + f);
    __attribute__((aligned(8))) u16 b[4];
#pragma unroll
    for (int j = 0; j < 4; ++j) b[j] = h16(v[j]);
    int ln = ((k0 & 31) >> 3) * 16 + row;
    *(uint2*)(xl + ((size_t)(k0 >> 5) * 64 + ln) * 8 + (k0 & 7)) = *(uint2*)b;
  }
  __syncthreads();

  f32x4 acc[3];
#pragma unroll
  for (int s = 0; s < 3; ++s) acc[s] = (f32x4){0.f, 0.f, 0.f, 0.f};

#pragma unroll 2
  for (int step = 0; step < 16; ++step) {
    f16x8 a = *(const f16x8*)(xl + ((size_t)step * 64 + lane) * 8);
#pragma unroll
    for (int s = 0; s < 3; ++s) {
      int sg = ng * 3 + s;
      f16x8 b = *(const f16x8*)(wlin + ((size_t)(sg * 16 + step) * 64 + lane) * 8);
      acc[s] = __builtin_amdgcn_mfma_f32_16x16x32_f16(a, b, acc[s], 0, 0, 0);
    }
  }
  __syncthreads();

#pragma unroll
  for (int s = 0; s < 3; ++s)
#pragma unroll
    for (int rr = 0; rr < 4; ++rr)
      scr[(g * 4 + rr) * 193 + ng * 48 + s * 16 + r16] = acc[s][rr];
  __syncthreads();

  u16* Ql = ws + (QL_B >> 1);
  u16* Kl = ws + (KL_B >> 1);
  u16* Vl = ws + (VL_B >> 1);
  const int batch = m0 >> 12;
  const int tile  = (m0 >> 5) & 127;
  const int half  = (m0 >> 4) & 1;

  {
    int t2 = tid & 127;
    int r  = t2 & 15, hh = (t2 >> 4) & 1, ch = t2 >> 5;
    int l31 = half * 16 + r;
    __attribute__((aligned(16))) u16 b[8];
    if (tid < 128) {
#pragma unroll
      for (int j = 0; j < 8; ++j) b[j] = h16(scr[r * 193 + 64 + ch * 16 + hh * 8 + j]);
      *(uint4*)(Kl + ((size_t)((batch * 128 + tile) * 4 + ch) * 64 + hh * 32 + l31) * 8) =
          *(uint4*)b;
    } else {
#pragma unroll
      for (int j = 0; j < 8; ++j) b[j] = h16(scr[r * 193 + ch * 16 + hh * 8 + j]);
      int qhalf = (m0 >> 5);
      *(uint4*)(Ql + ((size_t)(qhalf * 4 + ch) * 64 + hh * 32 + l31) * 8) = *(uint4*)b;
    }
  }
  {
    int z = tid & 1, l31 = (tid >> 1) & 31, hh = (tid >> 6) & 1, db = tid >> 7;
    int d = db * 32 + l31;
    __attribute__((aligned(8))) u16 b[4];
#pragma unroll
    for (int j = 0; j < 4; ++j) b[j] = h16(scr[(8 * z + 4 * hh + j) * 193 + 128 + d]);
    *(uint2*)(Vl + ((size_t)(((batch * 128 + tile) * 2 + db) * 2 + half) * 64 + hh * 32 + l31) *
                       8 + z * 4) = *(uint2*)b;
  }
}

// ---------------- flash attention: ALL-register K+V prefetch (no main-loop LDS) --------
// 256 blocks (XCD-bijective) x 512 thr (8 waves = 2 qg x 4 kq). Wave (qg,kq): q rows
// qb*64+qg*32, kv quarter kq*1024 = 32 tiles. K AND V in 2-deep register double-buffers
// (K's buffer was wave-private -> LDS staging was pure overhead, m169 lesson). Compiler
// emits minimal counted vmcnt waits. LDS used only for the two-pass merge (~37KB).
__global__ __launch_bounds__(512, 2) void attn_kernel(const u16* __restrict__ ws,
                                                      float* __restrict__ out) {
  __shared__ __attribute__((aligned(16))) float po[4][32][68];   // 34.8KB
  __shared__ float mls[8][32][2];                                // 2KB

  const int tid  = threadIdx.x;
  const int w    = tid >> 6;
  const int lane = tid & 63;
  const int l31  = lane & 31;
  const int h    = lane >> 5;
  const int qg   = w >> 2;
  const int kq   = w & 3;
  const int bx   = blockIdx.x;
  const int qb   = (bx & 7) * 32 + (bx >> 3);  // bijective: XCD gets contiguous q range
  const int bb   = qb >> 6;                    // batch

  const u16* Ql = ws + (QL_B >> 1);
  const u16* Kl = ws + (KL_B >> 1);
  const u16* Vl = ws + (VL_B >> 1);

  f16x8 qf[4];
#pragma unroll
  for (int ch = 0; ch < 4; ++ch)
    qf[ch] = *(const f16x8*)(Ql + ((size_t)((qb * 2 + qg) * 4 + ch) * 64 + lane) * 8);

  f32x16 oacc[2];
#pragma unroll
  for (int db = 0; db < 2; ++db)
#pragma unroll
    for (int r = 0; r < 16; ++r) oacc[db][r] = 0.f;
  float mrun = -INFINITY, lrun = 0.f;
  const float RTHR = 11.0f;

  const int t0 = bb * 128 + kq * 32;  // wave's private 32-tile kv range

  f16x8 k0r[4], k1r[4], v0r[2][2], v1r[2][2];
  auto loadK = [&](f16x8(&kk)[4], int t) {
#pragma unroll
    for (int ch = 0; ch < 4; ++ch)
      kk[ch] = *(const f16x8*)(Kl + (size_t)t * 2048 + (ch * 64 + lane) * 8);
  };
  auto loadV = [&](f16x8(&vv)[2][2], int t) {
#pragma unroll
    for (int db = 0; db < 2; ++db)
#pragma unroll
      for (int pp = 0; pp < 2; ++pp)
        vv[db][pp] = *(const f16x8*)(Vl + (size_t)t * 2048 + ((db * 2 + pp) * 64 + lane) * 8);
  };

  auto body = [&](f16x8(&kc)[4], f16x8(&kn)[4], f16x8(&vc)[2][2], f16x8(&vn)[2][2], int t,
                  bool last) {
    if (!last) {
      loadK(kn, t + 1);
      loadV(vn, t + 1);
    }

    // S^T = K * Q^T (compiler inserts counted vmcnt before first use of kc)
    f32x16 sac;
#pragma unroll
    for (int r = 0; r < 16; ++r) sac[r] = 0.f;
#pragma unroll
    for (int ch = 0; ch < 4; ++ch)
      sac = __builtin_amdgcn_mfma_f32_32x32x16_f16(kc[ch], qf[ch], sac, 0, 0, 0);

    // lane-local defer-max softmax, tree max
    float t8[8];
#pragma unroll
    for (int r = 0; r < 8; ++r) t8[r] = fmaxf(sac[2 * r], sac[2 * r + 1]);
    float t4a = fmaxf(t8[0], t8[1]), t4b = fmaxf(t8[2], t8[3]);
    float t4c = fmaxf(t8[4], t8[5]), t4d = fmaxf(t8[6], t8[7]);
    float mt = fmaxf(fmaxf(t4a, t4b), fmaxf(t4c, t4d));
    if (__any(mt > mrun + RTHR)) {
      float mtw  = fmaxf(mt, __shfl_xor(mt, 32));
      float nm   = fmaxf(mrun, mtw);
      float corr = ex2(mrun - nm);
      lrun *= corr;
      mrun = nm;
#pragma unroll
      for (int db = 0; db < 2; ++db)
#pragma unroll
        for (int r = 0; r < 16; ++r) oacc[db][r] *= corr;
    }
#pragma unroll
    for (int r = 0; r < 16; ++r) sac[r] = ex2(sac[r] - mrun);
    float s4[4];
#pragma unroll
    for (int r = 0; r < 4; ++r)
      s4[r] = (sac[4 * r] + sac[4 * r + 1]) + (sac[4 * r + 2] + sac[4 * r + 3]);
    lrun += (s4[0] + s4[1]) + (s4[2] + s4[3]);

    // P -> B-fragments of 32x32x8 directly (no cross-lane ops)
    f16x4 pb[4];
#pragma unroll
    for (int c = 0; c < 4; ++c) {
      u32x2 pk;
      pk[0] = pkrtz(sac[4 * c + 0], sac[4 * c + 1]);
      pk[1] = pkrtz(sac[4 * c + 2], sac[4 * c + 3]);
      pb[c] = __builtin_bit_cast(f16x4, pk);
    }

    // O^T += V^T * P^T
#pragma unroll
    for (int db = 0; db < 2; ++db)
#pragma unroll
      for (int pp = 0; pp < 2; ++pp) {
        f16x4 vlo = __builtin_shufflevector(vc[db][pp], vc[db][pp], 0, 1, 2, 3);
        f16x4 vhi = __builtin_shufflevector(vc[db][pp], vc[db][pp], 4, 5, 6, 7);
        oacc[db] = __builtin_amdgcn_mfma_f32_32x32x8f16(vlo, pb[2 * pp], oacc[db], 0, 0, 0);
        oacc[db] = __builtin_amdgcn_mfma_f32_32x32x8f16(vhi, pb[2 * pp + 1], oacc[db], 0, 0, 0);
      }
  };

  loadK(k0r, t0);
  loadV(v0r, t0);
#pragma unroll 1
  for (int p = 0; p < 16; ++p) {
    body(k0r, k1r, v0r, v1r, t0 + 2 * p, false);
    body(k1r, k0r, v1r, v0r, t0 + 2 * p + 1, p == 15);
  }

  lrun += __shfl_xor(lrun, 32);

  // ---- two-pass in-LDS merge (dedicated po/mls; no main-loop LDS to recycle) ----
  if (h == 0) {
    mls[w][l31][0] = mrun;
    mls[w][l31][1] = lrun;
  }
  __syncthreads();

#pragma unroll 1
  for (int g = 0; g < 2; ++g) {
    if (qg == g) {
      float mg = -INFINITY;
#pragma unroll
      for (int k2 = 0; k2 < 4; ++k2) mg = fmaxf(mg, mls[g * 4 + k2][l31][0]);
      float wgt = ex2(mrun - mg);
#pragma unroll
      for (int db = 0; db < 2; ++db)
#pragma unroll
        for (int gg = 0; gg < 4; ++gg) {
          f32x4 v = {oacc[db][4 * gg + 0] * wgt, oacc[db][4 * gg + 1] * wgt,
                     oacc[db][4 * gg + 2] * wgt, oacc[db][4 * gg + 3] * wgt};
          *(f32x4*)(&po[kq][l31][db * 32 + 8 * gg + 4 * h]) = v;
        }
    }
    __syncthreads();
    {
      int q = tid >> 4, c4 = (tid & 15) * 4;  // 512 threads = 32 rows x 16 col-groups
      float m2 = -INFINITY;
#pragma unroll
      for (int k2 = 0; k2 < 4; ++k2) m2 = fmaxf(m2, mls[g * 4 + k2][q][0]);
      float l2 = 0.f;
#pragma unroll
      for (int k2 = 0; k2 < 4; ++k2)
        l2 += mls[g * 4 + k2][q][1] * ex2(mls[g * 4 + k2][q][0] - m2);
      f32x4 s = (f32x4){0.f, 0.f, 0.f, 0.f};
#pragma unroll
      for (int k2 = 0; k2 < 4; ++k2) s += *(const f32x4*)(&po[k2][q][c4]);
      s *= (1.f / l2);
      *(f32x4*)(out + (size_t)(qb * 64 + g * 32 + q) * 64 + c4) = s;
    }
    __syncthreads();
  }
}

extern "C" void kernel_launch(void* const* d_in, const int* in_sizes, int n_in,
                              void* d_out, int out_size, void* d_ws, size_t ws_size,
                              hipStream_t stream) {
  const float* x  = (const float*)d_in[0];
  const float* Wq = (const float*)d_in[1];
  const float* Wk = (const float*)d_in[2];
  const float* Wv = (const float*)d_in[3];
  u16* ws = (u16*)d_ws;
  (void)in_sizes; (void)n_in; (void)out_size; (void)ws_size;

  wconv_kernel<<<96, 256, 0, stream>>>(Wq, Wk, Wv, ws + (WL_B >> 1));
  proj_kernel<<<1024, 256, 0, stream>>>(x, ws + (WL_B >> 1), ws);
  attn_kernel<<<256, 512, 0, stream>>>(ws, (float*)d_out);
}